// Round 13
// baseline (299.894 us; speedup 1.0000x reference)
//
#include <hip/hip_runtime.h>
#include <hip/hip_bf16.h>
#include <math.h>

#define M_TOKENS 4096
#define K_IN     4096
#define N_OUT    11008

#define BM 128
#define BN 256
#define BK 128
#define KTILES (K_IN / BK)   // 32

typedef int i32x4 __attribute__((ext_vector_type(4)));

__device__ __forceinline__ void async_copy16(const void* g, void* l) {
    __builtin_amdgcn_global_load_lds(
        (const __attribute__((address_space(1))) void*)g,
        (__attribute__((address_space(3))) void*)l, 16, 0, 0);
}

// ---- x fp32 -> int8, per-row (token) scale ----
__global__ __launch_bounds__(256) void quant_x_kernel(const float* __restrict__ x,
                                                      char* __restrict__ xq,
                                                      float* __restrict__ xs) {
    __shared__ float wmax[4];
    const int m = blockIdx.x;
    const int t = threadIdx.x;
    const float* row = x + (size_t)m * K_IN;
    float4 v[4];
    float lmax = 0.f;
#pragma unroll
    for (int p = 0; p < 4; ++p) {
        v[p] = *reinterpret_cast<const float4*>(row + p * 1024 + t * 4);
        lmax = fmaxf(lmax, fmaxf(fmaxf(fabsf(v[p].x), fabsf(v[p].y)),
                                 fmaxf(fabsf(v[p].z), fabsf(v[p].w))));
    }
#pragma unroll
    for (int off = 32; off >= 1; off >>= 1)
        lmax = fmaxf(lmax, __shfl_xor(lmax, off, 64));
    if ((t & 63) == 0) wmax[t >> 6] = lmax;
    __syncthreads();
    float gmax = fmaxf(fmaxf(wmax[0], wmax[1]), fmaxf(wmax[2], wmax[3]));
    gmax = fmaxf(gmax, 1e-20f);
    const float inv = 127.f / gmax;
    if (t == 0) xs[m] = gmax / 127.f;
#pragma unroll
    for (int p = 0; p < 4; ++p) {
        float vv[4] = {v[p].x, v[p].y, v[p].z, v[p].w};
        alignas(4) char c[4];
#pragma unroll
        for (int j = 0; j < 4; ++j) {
            float q = rintf(vv[j] * inv);
            q = fminf(fmaxf(q, -127.f), 127.f);
            c[j] = (char)(int)q;
        }
        *reinterpret_cast<unsigned*>(xq + (size_t)m * K_IN + p * 1024 + t * 4) =
            *reinterpret_cast<const unsigned*>(c);
    }
}

// ---- per-column weight scale, exact from (s,z): max_g max(|z-8s|,|z+7s|) ----
__global__ __launch_bounds__(256) void scale_w_kernel(const float* __restrict__ snz,
                                                      float* __restrict__ ws,
                                                      float* __restrict__ wsinv) {
    int n = blockIdx.x * 256 + threadIdx.x;
    if (n >= N_OUT) return;
    float m = 0.f;
#pragma unroll 4
    for (int g = 0; g < 32; ++g) {
        float s = snz[((size_t)g * N_OUT + n) * 2];
        float z = snz[((size_t)g * N_OUT + n) * 2 + 1];
        m = fmaxf(m, fmaxf(fabsf(z - 8.f * s), fabsf(z + 7.f * s)));
    }
    m = fmaxf(m, 1e-20f);
    ws[n] = m / 127.f;
    wsinv[n] = 127.f / m;
}

// ---- int4-code dequant -> int8 [n][k] (B^T layout), 8 k/thread ----
__global__ __launch_bounds__(256) void dequant_kernel(const int* __restrict__ wq,
                                                      const float* __restrict__ snz,
                                                      const float* __restrict__ wsinv,
                                                      char* __restrict__ wb) {
    size_t idx = (size_t)blockIdx.x * 256 + threadIdx.x;   // n*(K/8) + k8
    int n  = (int)(idx >> 9);         // K_IN/8 = 512
    int k8 = (int)(idx & 511);
    int g  = k8 >> 4;                 // (k8*8)/128
    const float* sz = snz + ((size_t)g * N_OUT + n) * 2;
    float scale = sz[0], zero = sz[1];
    float inv = wsinv[n];
    const int4* q4 = reinterpret_cast<const int4*>(wq + (size_t)n * K_IN + (size_t)k8 * 8);
    int4 qa = q4[0], qb = q4[1];
    int q[8] = {qa.x, qa.y, qa.z, qa.w, qb.x, qb.y, qb.z, qb.w};
    alignas(8) char t[8];
#pragma unroll
    for (int j = 0; j < 8; ++j) {
        float w = (float)(q[j] - 8) * scale + zero;
        float qq = rintf(w * inv);
        qq = fminf(fmaxf(qq, -127.f), 127.f);
        t[j] = (char)(int)qq;
    }
    *reinterpret_cast<uint2*>(wb + idx * 8) = *reinterpret_cast<const uint2*>(t);
}

// ====== 128x256 int8 GEMM — 4-wave blocks, 2 blocks/CU for cross-block overlap ======
// R12 landed the i8 win (203us GEMM) but stayed serialized: 1 block/CU means both
// waves on each SIMD are barrier-coupled. Here: 4-wave (2x2) blocks, 48KB single
// LDS buffer -> 2 independent blocks/CU (regs ~240<=256 -> 2 waves/SIMD, one per
// block; LDS 96KB). Per-CU pipe work IDENTICAL to R12 (192 ds_read + 512 MFMA
// per 65K outputs); the lever is purely that co-SIMD waves now come from
// barrier-INDEPENDENT blocks, so one block's DS/stage phases overlap the
// partner's MFMA phases (m114 mechanism). Compute phase: zero manual waits —
// compiler's precise lgkmcnt interleaves 24 reads with 64 MFMAs within the wave.
// Sync/tile: bare barrier (reads consumed via MFMA data-deps, round-3 invariant)
// + stage + vmcnt(0)+barrier (wait-then-barrier).

#define SCB()  __builtin_amdgcn_sched_barrier(0)
#define SBAR() { SCB(); __builtin_amdgcn_s_barrier(); SCB(); }
#define VM0BAR() { SCB(); asm volatile("s_waitcnt vmcnt(0)" ::: "memory"); \
                   __builtin_amdgcn_s_barrier(); SCB(); }

__global__ __launch_bounds__(256, 2) void gemm_i8_kernel(
        const char* __restrict__ Xq,
        const char* __restrict__ Wq,
        const float* __restrict__ xs,
        const float* __restrict__ ws,
        float* __restrict__ C) {
    __shared__ alignas(16) char smem[49152];   // A [128][128B] = 16KB, B [256][128B] = 32KB
    char* const ldsA = smem;
    char* const ldsB = smem + 16384;

    const int tid  = threadIdx.x;
    const int lane = tid & 63;
    const int wave = tid >> 6;      // 0..3
    const int wr   = wave >> 1;     // 0..1  (M half, 64 rows)
    const int wc   = wave & 1;      // 0..1  (N half, 128 cols)
    const int l15  = lane & 15;
    const int lrow = lane >> 3;     // staging row-in-chunk (= row & 7)
    const int ssw  = (((lane & 7) ^ lrow) << 4);   // pre-swizzled source col (bytes)

    // XCD-bijective swizzle (grid = 1376, 1376 % 8 == 0)
    unsigned bid = blockIdx.x;
    unsigned per = gridDim.x >> 3;               // 172
    unsigned swz = (bid & 7u) * per + (bid >> 3);
    const int tn = (int)(swz % (N_OUT / BN));    // 43
    const int tm = (int)(swz / (N_OUT / BN));    // 32
    const int m0 = tm * BM;
    const int n0 = tn * BN;

    // swizzled read column (bytes within a 128B row); K-step s toggles bit 6
    const int colswz = (((lane >> 4) << 4) ^ ((lane & 7) << 4));

    i32x4 acc[4][8];
#pragma unroll
    for (int i = 0; i < 4; ++i)
#pragma unroll
        for (int j = 0; j < 8; ++j) {
            i32x4 z = {0, 0, 0, 0};
            acc[i][j] = z;
        }

    // stage one full 48KB tile: A 4 + B 8 gload_lds per thread
    auto stage = [&](int kt) {
#pragma unroll
        for (int j = 0; j < 4; ++j) {
            int rm = j * 32 + wave * 8 + lrow;
            const char* g = Xq + (size_t)(m0 + rm) * K_IN + (size_t)kt * 128 + ssw;
            async_copy16(g, ldsA + rm * 128);
        }
#pragma unroll
        for (int j = 0; j < 8; ++j) {
            int rn = j * 32 + wave * 8 + lrow;
            const char* g = Wq + (size_t)(n0 + rn) * K_IN + (size_t)kt * 128 + ssw;
            async_copy16(g, ldsB + rn * 128);
        }
    };
    auto readA = [&](int mi, int s) -> i32x4 {
        return *(const i32x4*)(ldsA + (wr * 64 + mi * 16 + l15) * 128 + (colswz ^ (s << 6)));
    };
    auto readB = [&](int ni, int s) -> i32x4 {
        return *(const i32x4*)(ldsB + (wc * 128 + ni * 16 + l15) * 128 + (colswz ^ (s << 6)));
    };

    // ---- prologue ----
    stage(0);
    VM0BAR();

    for (int t = 0; t < KTILES; ++t) {
        // compute tile t: 24 ds_reads + 64 MFMA, compiler-interleaved (no manual waits)
#pragma unroll
        for (int s = 0; s < 2; ++s) {
            i32x4 aF[4], bF[8];
#pragma unroll
            for (int mi = 0; mi < 4; ++mi) aF[mi] = readA(mi, s);
#pragma unroll
            for (int ni = 0; ni < 8; ++ni) bF[ni] = readB(ni, s);
            __builtin_amdgcn_s_setprio(1);
#pragma unroll
            for (int mi = 0; mi < 4; ++mi)
#pragma unroll
                for (int ni = 0; ni < 8; ++ni)
                    acc[mi][ni] = __builtin_amdgcn_mfma_i32_16x16x64_i8(
                        aF[mi], bF[ni], acc[mi][ni], 0, 0, 0);
            __builtin_amdgcn_s_setprio(0);
        }
        SBAR();                       // all reads consumed (data-dep) -> safe to re-stage
        stage((t + 1) & (KTILES - 1)); // last iter: dead re-stage of tile 0, harmless
        VM0BAR();                     // wait-then-barrier: staged tile visible CU-wide
    }

    // ---- epilogue: D layout col=lane&15, row=(lane>>4)*4+e; scale by xs*ws ----
    const int r4 = (lane >> 4) << 2;
    float sn[8];
#pragma unroll
    for (int ni = 0; ni < 8; ++ni) sn[ni] = ws[n0 + wc * 128 + ni * 16 + l15];
#pragma unroll
    for (int mi = 0; mi < 4; ++mi) {
        const float4 xm = *reinterpret_cast<const float4*>(xs + m0 + wr * 64 + mi * 16 + r4);
        const float xv[4] = {xm.x, xm.y, xm.z, xm.w};
#pragma unroll
        for (int ni = 0; ni < 8; ++ni)
#pragma unroll
            for (int e = 0; e < 4; ++e) {
                int row = m0 + wr * 64 + mi * 16 + r4 + e;
                int col = n0 + wc * 128 + ni * 16 + l15;
                C[(size_t)row * N_OUT + col] = (float)acc[mi][ni][e] * xv[e] * sn[ni];
            }
    }
}

extern "C" void kernel_launch(void* const* d_in, const int* in_sizes, int n_in,
                              void* d_out, int out_size, void* d_ws, size_t ws_size,
                              hipStream_t stream) {
    const float* x   = (const float*)d_in[0];
    const int*   wq  = (const int*)d_in[1];
    const float* snz = (const float*)d_in[2];
    float* out = (float*)d_out;

    char*  Xq    = (char*)d_ws;                                   // 16 MB
    char*  Wq8   = (char*)d_ws + ((size_t)M_TOKENS * K_IN);       // 43 MB
    float* xs    = (float*)((char*)d_ws + (size_t)M_TOKENS * K_IN + (size_t)N_OUT * K_IN);
    float* ws    = xs + M_TOKENS;
    float* wsinv = ws + N_OUT;

    quant_x_kernel<<<M_TOKENS, 256, 0, stream>>>(x, Xq, xs);
    scale_w_kernel<<<(N_OUT + 255) / 256, 256, 0, stream>>>(snz, ws, wsinv);
    dequant_kernel<<<((size_t)N_OUT * K_IN) / 8 / 256, 256, 0, stream>>>(wq, snz, wsinv, Wq8);
    gemm_i8_kernel<<<(M_TOKENS / BM) * (N_OUT / BN), 256, 0, stream>>>(Xq, Wq8, xs, ws, out);
}

// Round 14
// 249.409 us; speedup vs baseline: 1.2024x; 1.2024x over previous
//
#include <hip/hip_runtime.h>
#include <hip/hip_bf16.h>
#include <math.h>

#define M_TOKENS 4096
#define K_IN     4096
#define N_OUT    11008

#define BM 256
#define BN 256
#define BK 128
#define KTILES (K_IN / BK)   // 32

typedef int i32x4 __attribute__((ext_vector_type(4)));

__device__ __forceinline__ void async_copy16(const void* g, void* l) {
    __builtin_amdgcn_global_load_lds(
        (const __attribute__((address_space(1))) void*)g,
        (__attribute__((address_space(3))) void*)l, 16, 0, 0);
}

// ---- x fp32 -> int8, per-row (token) scale ----
__global__ __launch_bounds__(256) void quant_x_kernel(const float* __restrict__ x,
                                                      char* __restrict__ xq,
                                                      float* __restrict__ xs) {
    __shared__ float wmax[4];
    const int m = blockIdx.x;
    const int t = threadIdx.x;
    const float* row = x + (size_t)m * K_IN;
    float4 v[4];
    float lmax = 0.f;
#pragma unroll
    for (int p = 0; p < 4; ++p) {
        v[p] = *reinterpret_cast<const float4*>(row + p * 1024 + t * 4);
        lmax = fmaxf(lmax, fmaxf(fmaxf(fabsf(v[p].x), fabsf(v[p].y)),
                                 fmaxf(fabsf(v[p].z), fabsf(v[p].w))));
    }
#pragma unroll
    for (int off = 32; off >= 1; off >>= 1)
        lmax = fmaxf(lmax, __shfl_xor(lmax, off, 64));
    if ((t & 63) == 0) wmax[t >> 6] = lmax;
    __syncthreads();
    float gmax = fmaxf(fmaxf(wmax[0], wmax[1]), fmaxf(wmax[2], wmax[3]));
    gmax = fmaxf(gmax, 1e-20f);
    const float inv = 127.f / gmax;
    if (t == 0) xs[m] = gmax / 127.f;
#pragma unroll
    for (int p = 0; p < 4; ++p) {
        float vv[4] = {v[p].x, v[p].y, v[p].z, v[p].w};
        alignas(4) char c[4];
#pragma unroll
        for (int j = 0; j < 4; ++j) {
            float q = rintf(vv[j] * inv);
            q = fminf(fmaxf(q, -127.f), 127.f);
            c[j] = (char)(int)q;
        }
        *reinterpret_cast<unsigned*>(xq + (size_t)m * K_IN + p * 1024 + t * 4) =
            *reinterpret_cast<const unsigned*>(c);
    }
}

// ---- per-column weight scale, exact from (s,z): max_g max(|z-8s|,|z+7s|) ----
__global__ __launch_bounds__(256) void scale_w_kernel(const float* __restrict__ snz,
                                                      float* __restrict__ ws,
                                                      float* __restrict__ wsinv) {
    int n = blockIdx.x * 256 + threadIdx.x;
    if (n >= N_OUT) return;
    float m = 0.f;
#pragma unroll 4
    for (int g = 0; g < 32; ++g) {
        float s = snz[((size_t)g * N_OUT + n) * 2];
        float z = snz[((size_t)g * N_OUT + n) * 2 + 1];
        m = fmaxf(m, fmaxf(fabsf(z - 8.f * s), fabsf(z + 7.f * s)));
    }
    m = fmaxf(m, 1e-20f);
    ws[n] = m / 127.f;
    wsinv[n] = 127.f / m;
}

// ---- int4-code dequant -> int8 [n][k] (B^T layout), 8 k/thread ----
__global__ __launch_bounds__(256) void dequant_kernel(const int* __restrict__ wq,
                                                      const float* __restrict__ snz,
                                                      const float* __restrict__ wsinv,
                                                      char* __restrict__ wb) {
    size_t idx = (size_t)blockIdx.x * 256 + threadIdx.x;   // n*(K/8) + k8
    int n  = (int)(idx >> 9);         // K_IN/8 = 512
    int k8 = (int)(idx & 511);
    int g  = k8 >> 4;                 // (k8*8)/128
    const float* sz = snz + ((size_t)g * N_OUT + n) * 2;
    float scale = sz[0], zero = sz[1];
    float inv = wsinv[n];
    const int4* q4 = reinterpret_cast<const int4*>(wq + (size_t)n * K_IN + (size_t)k8 * 8);
    int4 qa = q4[0], qb = q4[1];
    int q[8] = {qa.x, qa.y, qa.z, qa.w, qb.x, qb.y, qb.z, qb.w};
    alignas(8) char t[8];
#pragma unroll
    for (int j = 0; j < 8; ++j) {
        float w = (float)(q[j] - 8) * scale + zero;
        float qq = rintf(w * inv);
        qq = fminf(fmaxf(qq, -127.f), 127.f);
        t[j] = (char)(int)qq;
    }
    *reinterpret_cast<uint2*>(wb + idx * 8) = *reinterpret_cast<const uint2*>(t);
}

// ====== 256x256 int8 GEMM — R4's proven kk-balanced 4-phase schedule, BK=128 ======
// Measured best (round 12): GEMM ~203us @ MfmaUtil 40%, 0 bank conflicts,
// total 247.8us, absmax 12.0. Rounds 13's occupancy restructure and rounds
// 5-11's schedule/B-path variants all regressed or tied; this is the floor of
// the source-level structure: DS pipe (2304 cyc reads + ~500 writes per
// K-tile per CU) serialized against MFMA (2612 cyc), ~10% dispatch tail,
// pre-passes at their HBM floor.

#define SCB()  __builtin_amdgcn_sched_barrier(0)
#define SBAR() { SCB(); __builtin_amdgcn_s_barrier(); SCB(); }
#define LGKM0() { asm volatile("s_waitcnt lgkmcnt(0)" ::: "memory"); SCB(); }
#define VM4()  { asm volatile("s_waitcnt vmcnt(4)" ::: "memory"); SCB(); }

#define RD_AL(T, S) \
    _Pragma("unroll") for (int mi = 0; mi < 4; ++mi) aL[mi] = readA(T, mi, S);
#define RD_AH(T, S) \
    _Pragma("unroll") for (int mi = 0; mi < 4; ++mi) aH[mi] = readA(T, 4 + mi, S);
#define RD_B4(T, S) \
    _Pragma("unroll") for (int ni = 0; ni < 4; ++ni) bk[ni] = readB(T, ni, S);

#define MFMA16(AOFF, FRAG) \
    __builtin_amdgcn_s_setprio(1); \
    { \
        _Pragma("unroll") for (int mi = 0; mi < 4; ++mi) \
        _Pragma("unroll") for (int ni = 0; ni < 4; ++ni) \
            acc[AOFF + mi][ni] = __builtin_amdgcn_mfma_i32_16x16x64_i8( \
                FRAG[mi], bk[ni], acc[AOFF + mi][ni], 0, 0, 0); \
    } \
    __builtin_amdgcn_s_setprio(0);

// One K-tile: consume (CA,CB); stage next-tile units into (NA,NB); K1=t+1, K2=t+2.
#define TILE(CA, CB, NA, NB, K1, K2) \
    /* phA: aL x b (s0); drained by previous end-of-phD VM4 */ \
    RD_AL(CA, 0); RD_B4(CB, 0); \
    stageB(NB, K1, 1); \
    SBAR(); LGKM0(); \
    MFMA16(0, aL); \
    VM4(); SBAR();   /* drains CAu1 for phB */ \
    /* phB */ \
    RD_AH(CA, 0); \
    stageA(NA, K1, 0); \
    SBAR(); LGKM0(); \
    MFMA16(4, aH); \
    SBAR(); \
    /* phC: s1 of already-guaranteed data */ \
    RD_AL(CA, 1); RD_B4(CB, 1); \
    stageA(NA, K1, 1); \
    SBAR(); LGKM0(); \
    MFMA16(0, aL); \
    SBAR(); \
    /* phD */ \
    RD_AH(CA, 1); \
    stageB(CB, K2, 0); \
    SBAR(); LGKM0(); \
    MFMA16(4, aH); \
    VM4(); SBAR();   /* drains NAu0, NBu0, NBu1 for next tile's phA */

__global__ __launch_bounds__(512, 2) void gemm_i8_kernel(
        const char* __restrict__ Xq,
        const char* __restrict__ Wq,
        const float* __restrict__ xs,
        const float* __restrict__ ws,
        float* __restrict__ C) {
    __shared__ alignas(16) char smem[131072];
    char* const ldsA = smem;            // [2][256 rows][128 i8 = 128B]
    char* const ldsB = smem + 65536;

    const int tid  = threadIdx.x;
    const int lane = tid & 63;
    const int wave = tid >> 6;
    const int wr   = wave >> 2;     // 0..1  (M half)
    const int wc   = wave & 3;      // 0..3  (N quarter)
    const int l15  = lane & 15;
    const int lrow = lane >> 3;     // staging row-in-chunk
    const int ssw  = (((lane & 7) ^ lrow) << 4);   // pre-swizzled source col (bytes)

    // XCD-bijective swizzle (grid = 688, 688 % 8 == 0)
    unsigned bid = blockIdx.x;
    unsigned per = gridDim.x >> 3;               // 86
    unsigned swz = (bid & 7u) * per + (bid >> 3);
    const int tn = (int)(swz % (N_OUT / BN));    // 43
    const int tm = (int)(swz / (N_OUT / BN));    // 16
    const int m0 = tm * BM;
    const int n0 = tn * BN;

    // swizzled read column (bytes within a 128B row); K-step s toggles bit 6
    const int colswz = (((lane >> 4) << 4) ^ ((lane & 7) << 4));

    i32x4 acc[8][4];
#pragma unroll
    for (int i = 0; i < 8; ++i)
#pragma unroll
        for (int j = 0; j < 4; ++j) {
            i32x4 z = {0, 0, 0, 0};
            acc[i][j] = z;
        }
    i32x4 aL[4], aH[4], bk[4];

    // stage one 16KB unit (2 x global_load_lds/thread)
    auto stageA = [&](char* dstTile, int kt, int unit) {
#pragma unroll
        for (int j = 0; j < 2; ++j) {
            int c  = wave * 2 + j;
            int rb = (c >> 3) * 128 + (c & 7) * 8 + unit * 64;   // u0: rows 0-63,128-191
            const char* g = Xq + (size_t)(m0 + rb + lrow) * K_IN
                            + (size_t)kt * 128 + ssw;
            async_copy16(g, dstTile + rb * 128);
        }
    };
    auto stageB = [&](char* dstTile, int kt, int unit) {
#pragma unroll
        for (int j = 0; j < 2; ++j) {
            int c  = wave * 2 + j;
            int rb = (c >> 2) * 64 + (c & 3) * 8 + unit * 32;    // u0: rows 0-31 per 64-seg
            const char* g = Wq + (size_t)(n0 + rb + lrow) * K_IN
                            + (size_t)kt * 128 + ssw;
            async_copy16(g, dstTile + rb * 128);
        }
    };
    auto readA = [&](char* tile, int mi8, int s) -> i32x4 {
        return *(const i32x4*)(tile + (wr * 128 + mi8 * 16 + l15) * 128 + (colswz ^ (s << 6)));
    };
    auto readB = [&](char* tile, int ni4, int s) -> i32x4 {
        return *(const i32x4*)(tile + (wc * 64 + ni4 * 16 + l15) * 128 + (colswz ^ (s << 6)));
    };

    char* const A0 = ldsA;   char* const A1 = ldsA + 32768;
    char* const B0 = ldsB;   char* const B1 = ldsB + 32768;

    // ---- prologue: [B0u0, B0u1, A0u0, A0u1, B1u0]; drain first 3 units ----
    stageB(B0, 0, 0); stageB(B0, 0, 1); stageA(A0, 0, 0); stageA(A0, 0, 1);
    stageB(B1, 1, 0);
    VM4(); SBAR();

    for (int i = 0; i < KTILES / 2; ++i) {
        const int k1 = (2 * i + 1) & (KTILES - 1);
        const int k2 = (2 * i + 2) & (KTILES - 1);
        const int k3 = (2 * i + 3) & (KTILES - 1);   // wraps on last iters: dead-but-safe
        TILE(A0, B0, A1, B1, k1, k2)   // tile 2i   (buf0)
        TILE(A1, B1, A0, B0, k2, k3)   // tile 2i+1 (buf1)
    }

    // ---- epilogue: D layout col=lane&15, row=(lane>>4)*4+e; scale by xs*ws ----
    const int r4 = (lane >> 4) << 2;
    float sn[4];
#pragma unroll
    for (int nf = 0; nf < 4; ++nf) sn[nf] = ws[n0 + wc * 64 + nf * 16 + l15];
#pragma unroll
    for (int mi = 0; mi < 8; ++mi) {
        const float4 xm = *reinterpret_cast<const float4*>(xs + m0 + wr * 128 + mi * 16 + r4);
        const float xv[4] = {xm.x, xm.y, xm.z, xm.w};
#pragma unroll
        for (int nf = 0; nf < 4; ++nf)
#pragma unroll
            for (int e = 0; e < 4; ++e) {
                int row = m0 + wr * 128 + mi * 16 + r4 + e;
                int col = n0 + wc * 64 + nf * 16 + l15;
                C[(size_t)row * N_OUT + col] = (float)acc[mi][nf][e] * xv[e] * sn[nf];
            }
    }
}

extern "C" void kernel_launch(void* const* d_in, const int* in_sizes, int n_in,
                              void* d_out, int out_size, void* d_ws, size_t ws_size,
                              hipStream_t stream) {
    const float* x   = (const float*)d_in[0];
    const int*   wq  = (const int*)d_in[1];
    const float* snz = (const float*)d_in[2];
    float* out = (float*)d_out;

    char*  Xq    = (char*)d_ws;                                   // 16 MB
    char*  Wq8   = (char*)d_ws + ((size_t)M_TOKENS * K_IN);       // 43 MB
    float* xs    = (float*)((char*)d_ws + (size_t)M_TOKENS * K_IN + (size_t)N_OUT * K_IN);
    float* ws    = xs + M_TOKENS;
    float* wsinv = ws + N_OUT;

    quant_x_kernel<<<M_TOKENS, 256, 0, stream>>>(x, Xq, xs);
    scale_w_kernel<<<(N_OUT + 255) / 256, 256, 0, stream>>>(snz, ws, wsinv);
    dequant_kernel<<<((size_t)N_OUT * K_IN) / 8 / 256, 256, 0, stream>>>(wq, snz, wsinv, Wq8);
    gemm_i8_kernel<<<(M_TOKENS / BM) * (N_OUT / BN), 512, 0, stream>>>(Xq, Wq8, xs, ws, out);
}